// Round 5
// baseline (107.745 us; speedup 1.0000x reference)
//
#include <hip/hip_runtime.h>

#define B_ 16
#define QN 256
#define KN 256
#define DN 256
#define HN 256

#define LOG2E 1.4426950408889634f
#define TWOLOG2E 2.8853900817779268f  // exp2(x*this) = e^{2x}

// ---------------- Kernel A (fused): projections ----------------
// 16 rows per block. First half of grid: qs[b][q][h] = (queries@Wq)*scale (row-major).
// Second half:        ksT[b][h][k] = (keys@Wk)*scale  TRANSPOSED -- free, since thread h
// holds acc[0..15] = a full 16-k strip for its h; it stores 4x float4 directly.
__global__ __launch_bounds__(256) void proj_kernel(const float* __restrict__ Xq,
                                                   const float* __restrict__ Xk,
                                                   const float* __restrict__ Wq,
                                                   const float* __restrict__ Wk,
                                                   float* __restrict__ Yq,
                                                   float* __restrict__ YkT,
                                                   float scale) {
    const int nb = (int)gridDim.x >> 1;
    int blk = blockIdx.x;
    const bool is_q = blk < nb;
    const float* X;
    const float* W;
    if (is_q) { X = Xq; W = Wq; }
    else      { X = Xk; W = Wk; blk -= nb; }
    const int row0 = blk * 16;

    __shared__ float xl[16][DN];
    const int tid = threadIdx.x;

    {
        const float4* src = (const float4*)(X + (size_t)row0 * DN);
        float4* dst = (float4*)&xl[0][0];
#pragma unroll
        for (int i = 0; i < 4; ++i) dst[tid + 256 * i] = src[tid + 256 * i];
    }
    __syncthreads();

    const int h = tid;
    float acc[16];
#pragma unroll
    for (int r = 0; r < 16; ++r) acc[r] = 0.f;

    for (int d0 = 0; d0 < DN; d0 += 4) {
        float w0 = W[(size_t)(d0 + 0) * HN + h];
        float w1 = W[(size_t)(d0 + 1) * HN + h];
        float w2 = W[(size_t)(d0 + 2) * HN + h];
        float w3 = W[(size_t)(d0 + 3) * HN + h];
#pragma unroll
        for (int r = 0; r < 16; ++r) {
            float4 x = *(const float4*)&xl[r][d0];  // wave-uniform -> LDS broadcast
            acc[r] = fmaf(x.x, w0, acc[r]);
            acc[r] = fmaf(x.y, w1, acc[r]);
            acc[r] = fmaf(x.z, w2, acc[r]);
            acc[r] = fmaf(x.w, w3, acc[r]);
        }
    }

    if (is_q) {
#pragma unroll
        for (int r = 0; r < 16; ++r)
            Yq[(size_t)(row0 + r) * HN + h] = acc[r] * scale;
    } else {
        const int b = row0 >> 8, kloc = row0 & 255;
        float* dst = YkT + ((size_t)b * HN + h) * KN + kloc;
#pragma unroll
        for (int j = 0; j < 4; ++j) {
            float4 o = make_float4(acc[4 * j + 0] * scale, acc[4 * j + 1] * scale,
                                   acc[4 * j + 2] * scale, acc[4 * j + 3] * scale);
            *(float4*)&dst[4 * j] = o;
        }
    }
}

// ------------- Kernel B: ACC[b][q][k] = sum_h wv[h] * rcp(1 + exp2(qs+ksT)) ----------
// true score = Wsum - 2*ACC; Wsum constant per q-row -> softmax-invariant, never formed.
// NO LDS, NO barriers: per 8-h window, 8 lane-consecutive float4 loads of ksT (L1/L2
// dedup across the 16 q-blocks sharing a k-tile), 2 float4 q loads, wv scalar loads.
// vmcnt-counted loads let the compiler pipeline windows; trans pipe is the target floor.
__global__ __launch_bounds__(256, 2) void score_kernel(const float* __restrict__ QS,
                                                       const float* __restrict__ KT,
                                                       const float* __restrict__ wv,
                                                       const int* __restrict__ lens,
                                                       float* __restrict__ ACC) {
    const int b = blockIdx.z;
    const int k0 = blockIdx.x * 64;
    const int q0 = blockIdx.y * 16;
    const int len = lens[b];
    if (k0 >= len) return;  // whole tile masked -> never read downstream

    const int tid = threadIdx.x;
    const int q = tid >> 4;     // 0..15
    const int kg = tid & 15;    // owns k = k0 + 4*kg .. +3

    const float* qrow = QS + ((size_t)b * QN + q0 + q) * HN;
    const float* kt = KT + (size_t)b * HN * KN + k0 + (kg << 2);

    float acc0 = 0.f, acc1 = 0.f, acc2 = 0.f, acc3 = 0.f;

#pragma unroll 2
    for (int h0 = 0; h0 < HN; h0 += 8) {
        float4 kv[8];
#pragma unroll
        for (int u = 0; u < 8; ++u)
            kv[u] = *(const float4*)&kt[(size_t)(h0 + u) * KN];
        float4 qa = *(const float4*)&qrow[h0];
        float4 qb = *(const float4*)&qrow[h0 + 4];
        float4 wa = *(const float4*)&wv[h0];
        float4 wb = *(const float4*)&wv[h0 + 4];
        float qv[8] = {qa.x, qa.y, qa.z, qa.w, qb.x, qb.y, qb.z, qb.w};
        float wl[8] = {wa.x, wa.y, wa.z, wa.w, wb.x, wb.y, wb.z, wb.w};
#pragma unroll
        for (int u = 0; u < 8; ++u) {
            float e0 = __builtin_amdgcn_exp2f(qv[u] + kv[u].x);
            float e1 = __builtin_amdgcn_exp2f(qv[u] + kv[u].y);
            float e2 = __builtin_amdgcn_exp2f(qv[u] + kv[u].z);
            float e3 = __builtin_amdgcn_exp2f(qv[u] + kv[u].w);
            acc0 = fmaf(wl[u], __builtin_amdgcn_rcpf(1.f + e0), acc0);
            acc1 = fmaf(wl[u], __builtin_amdgcn_rcpf(1.f + e1), acc1);
            acc2 = fmaf(wl[u], __builtin_amdgcn_rcpf(1.f + e2), acc2);
            acc3 = fmaf(wl[u], __builtin_amdgcn_rcpf(1.f + e3), acc3);
        }
    }

    *(float4*)&ACC[((size_t)b * QN + q0 + q) * KN + k0 + (kg << 2)] =
        make_float4(acc0, acc1, acc2, acc3);
}

// ------------- Kernel C: masked softmax over (-2*ACC) then attn @ values -------------
__global__ __launch_bounds__(256) void softmax_pv_kernel(const float* __restrict__ ACC,
                                                         const float* __restrict__ V,
                                                         const int* __restrict__ lens,
                                                         float* __restrict__ OUT) {
    const int b = blockIdx.y;
    const int q0 = blockIdx.x * 8;
    const int len = lens[b];

    __shared__ float sl[8][256];
    const int tid = threadIdx.x;

    const float* src = ACC + ((size_t)b * QN + q0) * KN;
#pragma unroll
    for (int i = tid; i < 8 * 256; i += 256) {
        int r = i >> 8, k = i & 255;
        float v = src[r * KN + k];
        sl[r][k] = (k < len) ? (-2.f * v) : -1e6f;
    }
    __syncthreads();

    const int wave = tid >> 6, lane = tid & 63;
    for (int r = wave; r < 8; r += 4) {
        float x0 = sl[r][lane];
        float x1 = sl[r][lane + 64];
        float x2 = sl[r][lane + 128];
        float x3 = sl[r][lane + 192];
        float m = fmaxf(fmaxf(x0, x1), fmaxf(x2, x3));
#pragma unroll
        for (int off = 32; off; off >>= 1) m = fmaxf(m, __shfl_xor(m, off, 64));
        float p0 = __builtin_amdgcn_exp2f((x0 - m) * LOG2E);
        float p1 = __builtin_amdgcn_exp2f((x1 - m) * LOG2E);
        float p2 = __builtin_amdgcn_exp2f((x2 - m) * LOG2E);
        float p3 = __builtin_amdgcn_exp2f((x3 - m) * LOG2E);
        float s = (p0 + p1) + (p2 + p3);
#pragma unroll
        for (int off = 32; off; off >>= 1) s += __shfl_xor(s, off, 64);
        float inv = 1.f / s;
        sl[r][lane] = p0 * inv;
        sl[r][lane + 64] = p1 * inv;
        sl[r][lane + 128] = p2 * inv;
        sl[r][lane + 192] = p3 * inv;
    }
    __syncthreads();

    const int d = tid;
    float out_acc[8];
#pragma unroll
    for (int r = 0; r < 8; ++r) out_acc[r] = 0.f;

    const float* vbase = V + (size_t)b * KN * DN + d;
    const int len4 = (len + 3) & ~3;
    for (int k = 0; k < len4; k += 4) {
        float v0 = vbase[(size_t)(k + 0) * DN];
        float v1 = vbase[(size_t)(k + 1) * DN];
        float v2 = vbase[(size_t)(k + 2) * DN];
        float v3 = vbase[(size_t)(k + 3) * DN];
#pragma unroll
        for (int r = 0; r < 8; ++r) {
            float4 a = *(const float4*)&sl[r][k];
            out_acc[r] = fmaf(a.x, v0, out_acc[r]);
            out_acc[r] = fmaf(a.y, v1, out_acc[r]);
            out_acc[r] = fmaf(a.z, v2, out_acc[r]);
            out_acc[r] = fmaf(a.w, v3, out_acc[r]);
        }
    }
    float* obase = OUT + ((size_t)b * QN + q0) * DN + d;
#pragma unroll
    for (int r = 0; r < 8; ++r) obase[(size_t)r * DN] = out_acc[r];
}

extern "C" void kernel_launch(void* const* d_in, const int* in_sizes, int n_in,
                              void* d_out, int out_size, void* d_ws, size_t ws_size,
                              hipStream_t stream) {
    const float* queries = (const float*)d_in[0];
    const float* keys    = (const float*)d_in[1];
    const float* values  = (const float*)d_in[2];
    const int*   lens    = (const int*)d_in[3];
    const float* Wq      = (const float*)d_in[4];
    const float* Wk      = (const float*)d_in[5];
    const float* wv      = (const float*)d_in[6];
    float* out = (float*)d_out;

    float* qs  = (float*)d_ws;                       // [B,Q,H]  4 MB (row-major)
    float* ksT = qs + (size_t)B_ * QN * HN;          // [B,H,K]  4 MB (transposed)
    float* acc = ksT + (size_t)B_ * HN * KN;         // [B,Q,K]  4 MB

    proj_kernel<<<(B_ * QN + B_ * KN) / 16, 256, 0, stream>>>(
        queries, keys, Wq, Wk, qs, ksT, TWOLOG2E);

    dim3 gB(KN / 64, QN / 16, B_);
    score_kernel<<<gB, 256, 0, stream>>>(qs, ksT, wv, lens, acc);

    dim3 gC(QN / 8, B_);
    softmax_pv_kernel<<<gC, 256, 0, stream>>>(acc, values, lens, out);
}